// Round 4
// baseline (567.612 us; speedup 1.0000x reference)
//
#include <hip/hip_runtime.h>
#include <hip/hip_bf16.h>
#include <stdint.h>

typedef float f32x4 __attribute__((ext_vector_type(4)));
typedef float fvec4 __attribute__((ext_vector_type(4)));
typedef short bf16x8 __attribute__((ext_vector_type(8)));

#define HALF_K 24576
#define NUMELK 49152
#define BATCH  8192
#define BM 256
#define BN 256
#define BK 64

__device__ __forceinline__ short f2bf(float f) {
  __hip_bfloat16 h = __float2bfloat16(f);
  return __builtin_bit_cast(short, h);
}

// global->LDS DMA, 16B per lane. LDS dest is wave-uniform base (+lane*16 by HW);
// global src is per-lane.
__device__ __forceinline__ void gload_lds16(const short* g, short* l) {
  __builtin_amdgcn_global_load_lds(
      (const __attribute__((address_space(1))) unsigned*)g,
      (__attribute__((address_space(3))) unsigned*)l, 16, 0, 0);
}

// ---------------- prep: B pre-tiled + pre-swizzled bf16 ----------------
// Logical B[col][k], col 0..255 over combined-K (col<128: w_aff_W row col;
// col>=128: b_aff_W row col-128 with K-halves swapped).
// Stored as per-K-tile contiguous 32KB tiles so gemm can global_load_lds it:
//   Bprep[KT*16384 + col*64 + ((kc ^ (col&7))<<3) + e],  k = KT*64 + kc*8 + e
__global__ __launch_bounds__(256)
void nnue_prep(const float* __restrict__ wW, const float* __restrict__ bW,
               short* __restrict__ Bprep) {
  int gid = blockIdx.x * 256 + threadIdx.x;   // grid 6144 -> 1,572,864 chunks
  int KT  = gid >> 11;                        // 0..767
  int rem = gid & 2047;
  int col = rem >> 3;                         // 0..255
  int kc  = rem & 7;
  int kg  = KT * 64 + kc * 8;
  const float* src;
  if (col < 128) {
    src = wW + (size_t)col * NUMELK + kg;
  } else {
    int kk = (kg < HALF_K) ? (kg + HALF_K) : (kg - HALF_K);
    src = bW + (size_t)(col - 128) * NUMELK + kk;
  }
  fvec4 v0 = ((const fvec4*)src)[0];
  fvec4 v1 = ((const fvec4*)src)[1];
  bf16x8 o;
  o[0] = f2bf(v0[0]); o[1] = f2bf(v0[1]); o[2] = f2bf(v0[2]); o[3] = f2bf(v0[3]);
  o[4] = f2bf(v1[0]); o[5] = f2bf(v1[1]); o[6] = f2bf(v1[2]); o[7] = f2bf(v1[3]);
  *(bf16x8*)(Bprep + (size_t)KT * 16384 + col * 64 + ((kc ^ (col & 7)) << 3)) = o;
}

// ---------------- main GEMM: [8192 x 49152] x [49152 x 256] ----------------
// 256x256 tile, BK=64, 8 waves (2M x 4N), per-wave 128x64 output, acc[8][4].
// 2-phase dbuf: A reg-staged (fp32->bf16), B via global_load_lds of the
// pre-swizzled tiles. One barrier per iter. S=8 K-split, ks = XCD id so each
// XCD's 3.07MB B chunk is L2-resident.
__global__ __launch_bounds__(512, 2)
void nnue_gemm(const float* __restrict__ white, const float* __restrict__ black,
               const short* __restrict__ Bprep, float* __restrict__ partial,
               int kchunk, int S) {
  __shared__ short Alds[2][BM * BK];   // 64 KB total, chunk-XOR swizzled by (row&7)
  __shared__ short Blds[2][BN * BK];   // 64 KB total, swizzle baked in by prep

  const int t    = threadIdx.x;
  const int lane = t & 63;
  const int wid  = t >> 6;

  // XCD-grouped decode: blocks on one XCD share ks (same B chunk in its L2)
  const int bid = blockIdx.x;          // 32*S blocks
  const int xcd = bid & 7, i = bid >> 3;
  const int xpk = 8 / S;               // S in {1,2,4,8}
  const int ks  = xcd / xpk;
  const int mt  = (xcd % xpk) * (32 / xpk) + i;
  const int m0  = mt * BM;
  const int k0  = ks * kchunk;
  const int KT0 = k0 / BK;

  f32x4 acc[8][4];
  const f32x4 zero = {0.f, 0.f, 0.f, 0.f};
#pragma unroll
  for (int a = 0; a < 8; ++a)
#pragma unroll
    for (int b = 0; b < 4; ++b) acc[a][b] = zero;

  const int arow = t >> 1;   // 0..255
  const int ah   = t & 1;    // which 32-float half of the row's 64 k-values
  const int wm = wid >> 2, wn = wid & 3;
  const int l15 = lane & 15, l4 = lane >> 4;

  const size_t arow_off = (size_t)(m0 + arow) * HALF_K + ah * 32;

  fvec4 va[8];               // 32 VGPR A staging (one tile in flight)

  auto issueA = [&](int kg) {
    const float* A; int ka;
    if (kg < HALF_K) { A = white; ka = kg; } else { A = black; ka = kg - HALF_K; }
    const float* asrc = A + arow_off + ka;
#pragma unroll
    for (int j = 0; j < 8; ++j) va[j] = ((const fvec4*)asrc)[j];
  };

  auto issueB = [&](int kt_glob, int buf) {
    const short* src = Bprep + (size_t)kt_glob * (BN * BK) + wid * 2048 + lane * 8;
    short* dst = &Blds[buf][wid * 2048];
#pragma unroll
    for (int j = 0; j < 4; ++j)
      gload_lds16(src + j * 512, dst + j * 512);
  };

  auto writeA = [&](int buf) {
    short* Ab = &Alds[buf][arow * 64];
#pragma unroll
    for (int c = 0; c < 4; ++c) {
      bf16x8 o;
      o[0] = f2bf(va[2*c][0]);   o[1] = f2bf(va[2*c][1]);
      o[2] = f2bf(va[2*c][2]);   o[3] = f2bf(va[2*c][3]);
      o[4] = f2bf(va[2*c+1][0]); o[5] = f2bf(va[2*c+1][1]);
      o[6] = f2bf(va[2*c+1][2]); o[7] = f2bf(va[2*c+1][3]);
      int kc = ah * 4 + c;
      *(bf16x8*)(Ab + ((kc ^ (arow & 7)) << 3)) = o;
    }
  };

  const int niter = kchunk / BK;

  // prologue: tile 0
  issueB(KT0, 0);
  issueA(k0);
  writeA(0);
  __syncthreads();

  for (int kt = 0; kt < niter; ++kt) {
    const int cur = kt & 1;
    const bool hn = (kt + 1 < niter);
    if (hn) {
      issueB(KT0 + kt + 1, cur ^ 1);     // DMA in flight across compute
      issueA(k0 + (kt + 1) * BK);        // regs in flight across compute
    }

    const short* Ab = Alds[cur];
    const short* Bb = Blds[cur];
#pragma unroll
    for (int kstep = 0; kstep < 2; ++kstep) {
      const int kc = kstep * 4 + l4;
      bf16x8 bfr[4];
#pragma unroll
      for (int nf = 0; nf < 4; ++nf) {
        int col = wn * 64 + nf * 16 + l15;
        bfr[nf] = *(const bf16x8*)&Bb[col * 64 + ((kc ^ (col & 7)) << 3)];
      }
#pragma unroll
      for (int mf = 0; mf < 8; ++mf) {
        int row = wm * 128 + mf * 16 + l15;
        bf16x8 af = *(const bf16x8*)&Ab[row * 64 + ((kc ^ (row & 7)) << 3)];
#pragma unroll
        for (int nf = 0; nf < 4; ++nf)
          acc[mf][nf] = __builtin_amdgcn_mfma_f32_16x16x32_bf16(af, bfr[nf], acc[mf][nf], 0, 0, 0);
      }
    }

    if (hn) writeA(cur ^ 1);   // vmcnt wait on A lands here, after compute
    __syncthreads();           // single barrier per iteration
  }

  // ---- epilogue: C/D layout col=lane&15, row=(lane>>4)*4+r   [m89]
  float* P = partial + ((size_t)ks * BATCH + m0) * 256;
#pragma unroll
  for (int mf = 0; mf < 8; ++mf) {
    int row = wm * 128 + mf * 16 + l4 * 4;
#pragma unroll
    for (int nf = 0; nf < 4; ++nf) {
      int col = wn * 64 + nf * 16 + l15;
#pragma unroll
      for (int rr = 0; rr < 4; ++rr)
        P[(size_t)(row + rr) * 256 + col] = acc[mf][nf][rr];
    }
  }
}

// ---------------- tail: partial-reduce + pov mix + relu + fc0..fc3 ----------------
__global__ __launch_bounds__(256)
void nnue_tail(const float* __restrict__ partial, int S,
               const float* __restrict__ pov,
               const float* __restrict__ waffb, const float* __restrict__ baffb,
               const float* __restrict__ fc0W, const float* __restrict__ fc0b,
               const float* __restrict__ fc1W, const float* __restrict__ fc1b,
               const float* __restrict__ fc2W, const float* __restrict__ fc2b,
               const float* __restrict__ fc3W, const float* __restrict__ fc3b,
               float* __restrict__ out) {
  __shared__ float w0s[32 * 256];   // stored at [(j<<8) | ((k+j)&255)]
  __shared__ float w1s[32 * 32];    // [(j<<5) | ((k+j)&31)]
  __shared__ float w2s[32 * 64];    // [(j<<6) | ((k+j)&63)]
  __shared__ float w3s[96];
  __shared__ float b0s[32], b1s[32], b2s[32];
  __shared__ float base_s[4][256];
  __shared__ float b3s;

  const int t = threadIdx.x;
  for (int i = t; i < 8192; i += 256) { int j = i >> 8, k = i & 255; w0s[(j << 8) | ((k + j) & 255)] = fc0W[i]; }
  for (int i = t; i < 1024; i += 256) { int j = i >> 5, k = i & 31;  w1s[(j << 5) | ((k + j) & 31)]  = fc1W[i]; }
  for (int i = t; i < 2048; i += 256) { int j = i >> 6, k = i & 63;  w2s[(j << 6) | ((k + j) & 63)]  = fc2W[i]; }
  if (t < 96) w3s[t] = fc3W[t];
  if (t < 32) { b0s[t] = fc0b[t]; b1s[t] = fc1b[t]; b2s[t] = fc2b[t]; }
  if (t == 0) b3s = fc3b[0];
  __syncthreads();

  const int wid = t >> 6, lane = t & 63;
  const int m = blockIdx.x * 4 + wid;
  const float pv = pov[m];

  // lane l holds concat[w_,b_] cols 4l..4l+3 (summed over K-splits, +bias)
  float val[4];
  {
    const float* p = partial + (size_t)m * 256 + lane * 4;
    fvec4 a = *(const fvec4*)p;
    for (int s = 1; s < S; ++s) a += *(const fvec4*)(p + (size_t)s * BATCH * 256);
    const int c0 = lane * 4;
#pragma unroll
    for (int j = 0; j < 4; ++j) {
      int c = c0 + j;
      float bias = (c < 128) ? waffb[c] : baffb[c - 128];
      val[j] = a[j] + bias;
    }
  }
#pragma unroll
  for (int j = 0; j < 4; ++j) {
    float other = __shfl(val[j], lane ^ 32, 64);   // partner holds the b_/w_ counterpart
    if (lane < 32) {
      int c = lane * 4 + j;
      float w = val[j], b = other;
      base_s[wid][c]       = fmaxf(pv * w + (1.f - pv) * b, 0.f);
      base_s[wid][c + 128] = fmaxf(pv * b + (1.f - pv) * w, 0.f);
    }
  }
  __syncthreads();

  const int j = lane & 31, half = lane >> 5;
  const float* bs = &base_s[wid][0];

  // fc0: each (j,half) pair sums 128 terms, then combines across halves
  float s0 = 0.f;
  for (int k = 0; k < 128; ++k) {
    int kk = half * 128 + k;
    s0 += bs[kk] * w0s[(j << 8) | ((kk + j) & 255)];
  }
  s0 += __shfl(s0, lane ^ 32, 64);
  float x0 = fmaxf(s0 + b0s[j], 0.f);

  // fc1 (32x32)
  float s1 = 0.f;
  for (int k = 0; k < 32; ++k)
    s1 += __shfl(x0, k, 64) * w1s[(j << 5) | ((k + j) & 31)];
  float x1 = fmaxf(s1 + b1s[j], 0.f);

  // fc2 (32x64), input = [x0, x1]
  float s2 = 0.f;
  for (int k = 0; k < 32; ++k) {
    s2 += __shfl(x0, k, 64) * w2s[(j << 6) | ((k + j) & 63)];
    s2 += __shfl(x1, k, 64) * w2s[(j << 6) | ((k + 32 + j) & 63)];
  }
  float x2 = fmaxf(s2 + b2s[j], 0.f);

  // fc3 (1x96), input = [x0, x1, x2]
  float s3 = 0.f;
  for (int k = 0; k < 32; ++k) {
    s3 += __shfl(x0, k, 64) * w3s[k];
    s3 += __shfl(x1, k, 64) * w3s[32 + k];
    s3 += __shfl(x2, k, 64) * w3s[64 + k];
  }
  if (lane == 0) out[m] = s3 + b3s;
}

extern "C" void kernel_launch(void* const* d_in, const int* in_sizes, int n_in,
                              void* d_out, int out_size, void* d_ws, size_t ws_size,
                              hipStream_t stream) {
  const float* pov   = (const float*)d_in[0];
  const float* white = (const float*)d_in[1];
  const float* black = (const float*)d_in[2];
  const float* wW    = (const float*)d_in[3];
  const float* wb    = (const float*)d_in[4];
  const float* bW    = (const float*)d_in[5];
  const float* bb    = (const float*)d_in[6];
  const float* fc0W  = (const float*)d_in[7];
  const float* fc0b  = (const float*)d_in[8];
  const float* fc1W  = (const float*)d_in[9];
  const float* fc1b  = (const float*)d_in[10];
  const float* fc2W  = (const float*)d_in[11];
  const float* fc2b  = (const float*)d_in[12];
  const float* fc3W  = (const float*)d_in[13];
  const float* fc3b  = (const float*)d_in[14];
  float* out = (float*)d_out;

  short* Bprep = (short*)d_ws;
  const size_t BWS_BYTES = (size_t)256 * NUMELK * 2;      // 25,165,824
  float* partial = (float*)((char*)d_ws + BWS_BYTES);
  const size_t PART1 = (size_t)BATCH * 256 * 4;           // 8,388,608

  int S = 8;                                              // K-split: 256 blocks = 1/CU
  if (ws_size < BWS_BYTES + 8 * PART1) S = 4;
  if (ws_size < BWS_BYTES + 4 * PART1) S = 2;
  if (ws_size < BWS_BYTES + 2 * PART1) S = 1;

  nnue_prep<<<dim3(6144), 256, 0, stream>>>(wW, bW, Bprep);
  nnue_gemm<<<dim3(32 * S), 512, 0, stream>>>(white, black, Bprep, partial, NUMELK / S, S);
  nnue_tail<<<dim3(BATCH / 4), 256, 0, stream>>>(partial, S, pov, wb, bb,
      fc0W, fc0b, fc1W, fc1b, fc2W, fc2b, fc3W, fc3b, out);
}

// Round 5
// 447.147 us; speedup vs baseline: 1.2694x; 1.2694x over previous
//
#include <hip/hip_runtime.h>
#include <hip/hip_bf16.h>
#include <stdint.h>

typedef float f32x4 __attribute__((ext_vector_type(4)));
typedef float fvec4 __attribute__((ext_vector_type(4)));
typedef short bf16x8 __attribute__((ext_vector_type(8)));
typedef short bf16x4 __attribute__((ext_vector_type(4)));

#define HALF_K 24576
#define NUMELK 49152
#define BATCH  8192
#define BM 256
#define BN 256
#define BK 64

__device__ __forceinline__ short f2bf(float f) {
  __hip_bfloat16 h = __float2bfloat16(f);
  return __builtin_bit_cast(short, h);
}

// global->LDS DMA, 16B per lane. LDS dest is wave-uniform base (+lane*16 by HW);
// global src is per-lane.
__device__ __forceinline__ void gload_lds16(const short* g, short* l) {
  __builtin_amdgcn_global_load_lds(
      (const __attribute__((address_space(1))) unsigned*)g,
      (__attribute__((address_space(3))) unsigned*)l, 16, 0, 0);
}

// ---------------- prep: B pre-tiled + pre-swizzled bf16 ----------------
// Logical B[col][k], col 0..255 over combined-K (col<128: w_aff_W row col;
// col>=128: b_aff_W row col-128 with K-halves swapped).
// Stored as per-K-tile contiguous 32KB tiles so gemm can global_load_lds it:
//   Bprep[KT*16384 + col*64 + ((kc ^ (col&7))<<3) + e],  k = KT*64 + kc*8 + e
__global__ __launch_bounds__(256)
void nnue_prep(const float* __restrict__ wW, const float* __restrict__ bW,
               short* __restrict__ Bprep) {
  int gid = blockIdx.x * 256 + threadIdx.x;   // grid 6144 -> 1,572,864 chunks
  int KT  = gid >> 11;                        // 0..767
  int rem = gid & 2047;
  int col = rem >> 3;                         // 0..255
  int kc  = rem & 7;
  int kg  = KT * 64 + kc * 8;
  const float* src;
  if (col < 128) {
    src = wW + (size_t)col * NUMELK + kg;
  } else {
    int kk = (kg < HALF_K) ? (kg + HALF_K) : (kg - HALF_K);
    src = bW + (size_t)(col - 128) * NUMELK + kk;
  }
  fvec4 v0 = ((const fvec4*)src)[0];
  fvec4 v1 = ((const fvec4*)src)[1];
  bf16x8 o;
  o[0] = f2bf(v0[0]); o[1] = f2bf(v0[1]); o[2] = f2bf(v0[2]); o[3] = f2bf(v0[3]);
  o[4] = f2bf(v1[0]); o[5] = f2bf(v1[1]); o[6] = f2bf(v1[2]); o[7] = f2bf(v1[3]);
  *(bf16x8*)(Bprep + (size_t)KT * 16384 + col * 64 + ((kc ^ (col & 7)) << 3)) = o;
}

// ---------------- main GEMM: [8192 x 49152] x [49152 x 256] ----------------
// 256x256 tile, BK=64, 8 waves (2M x 4N), per-wave 128x64 output, acc[8][4].
// 2-phase dbuf, one barrier per iter. A staged COALESCED: 16 consecutive lanes
// cover one row's 256B contiguously (each vmem instr = 16 cache lines, each
// touched once -> minimum transaction count). B via global_load_lds from the
// pre-swizzled tiles. S=8 K-split, ks = XCD id -> B chunk (3.07MB) L2-resident.
__global__ __launch_bounds__(512, 1)
void nnue_gemm(const float* __restrict__ white, const float* __restrict__ black,
               const short* __restrict__ Bprep, float* __restrict__ partial,
               int kchunk, int S) {
  __shared__ short Alds[2][BM * BK];   // 64 KB total, chunk-XOR swizzled by (row&7)
  __shared__ short Blds[2][BN * BK];   // 64 KB total, swizzle baked in by prep

  const int t    = threadIdx.x;
  const int lane = t & 63;
  const int wid  = t >> 6;

  // XCD-grouped decode: blocks on one XCD share ks (same B chunk in its L2)
  const int bid = blockIdx.x;          // 32*S blocks
  const int xcd = bid & 7, i = bid >> 3;
  const int xpk = 8 / S;               // S in {1,2,4,8}
  const int ks  = xcd / xpk;
  const int mt  = (xcd % xpk) * (32 / xpk) + i;
  const int m0  = mt * BM;
  const int k0  = ks * kchunk;
  const int KT0 = k0 / BK;

  f32x4 acc[8][4];
  const f32x4 zero = {0.f, 0.f, 0.f, 0.f};
#pragma unroll
  for (int a = 0; a < 8; ++a)
#pragma unroll
    for (int b = 0; b < 4; ++b) acc[a][b] = zero;

  const int wm = wid >> 2, wn = wid & 3;
  const int l15 = lane & 15, l4 = lane >> 4;

  // A staging map: pass j (0..7): thread t covers row 32j + (t>>4),
  // 16B fp32 chunk (t&15) within the row's 64 floats.
  const int rbase = t >> 4;            // 0..31
  const int cchunk = t & 15;           // 16B fp32 chunk (4 floats)
  const size_t a_off = (size_t)(m0 + rbase) * HALF_K + cchunk * 4;
  const int swz = ((cchunk >> 1) ^ (rbase & 7)) << 3;  // loop-invariant (row&7 == rbase&7)
  const int halfsh = (cchunk & 1) * 4;                 // shorts offset of 8B half

  fvec4 va[8];               // 32 VGPR A staging (one tile in flight)

  auto issueA = [&](int kg) {
    const float* A; int ka;
    if (kg < HALF_K) { A = white; ka = kg; } else { A = black; ka = kg - HALF_K; }
    const float* base = A + a_off + ka;
#pragma unroll
    for (int j = 0; j < 8; ++j)
      va[j] = *(const fvec4*)(base + (size_t)32 * j * HALF_K);
  };

  auto issueB = [&](int kt_glob, int buf) {
    const short* src = Bprep + (size_t)kt_glob * (BN * BK) + wid * 2048 + lane * 8;
    short* dst = &Blds[buf][wid * 2048];
#pragma unroll
    for (int j = 0; j < 4; ++j)
      gload_lds16(src + j * 512, dst + j * 512);
  };

  auto writeA = [&](int buf) {
#pragma unroll
    for (int j = 0; j < 8; ++j) {
      int row = 32 * j + rbase;
      bf16x4 o;
      o[0] = f2bf(va[j][0]); o[1] = f2bf(va[j][1]);
      o[2] = f2bf(va[j][2]); o[3] = f2bf(va[j][3]);
      *(bf16x4*)&Alds[buf][row * 64 + swz + halfsh] = o;
    }
  };

  const int niter = kchunk / BK;

  // prologue: tile 0
  issueB(KT0, 0);
  issueA(k0);
  writeA(0);
  __syncthreads();

  for (int kt = 0; kt < niter; ++kt) {
    const int cur = kt & 1;
    const bool hn = (kt + 1 < niter);
    if (hn) {
      issueB(KT0 + kt + 1, cur ^ 1);     // DMA in flight across compute
      issueA(k0 + (kt + 1) * BK);        // regs in flight across compute
    }

    const short* Ab = Alds[cur];
    const short* Bb = Blds[cur];
#pragma unroll
    for (int kstep = 0; kstep < 2; ++kstep) {
      const int kc = kstep * 4 + l4;
      bf16x8 bfr[4];
#pragma unroll
      for (int nf = 0; nf < 4; ++nf) {
        int col = wn * 64 + nf * 16 + l15;
        bfr[nf] = *(const bf16x8*)&Bb[col * 64 + ((kc ^ (col & 7)) << 3)];
      }
#pragma unroll
      for (int mf = 0; mf < 8; ++mf) {
        int row = wm * 128 + mf * 16 + l15;
        bf16x8 af = *(const bf16x8*)&Ab[row * 64 + ((kc ^ (row & 7)) << 3)];
#pragma unroll
        for (int nf = 0; nf < 4; ++nf)
          acc[mf][nf] = __builtin_amdgcn_mfma_f32_16x16x32_bf16(af, bfr[nf], acc[mf][nf], 0, 0, 0);
      }
    }

    if (hn) writeA(cur ^ 1);   // vmcnt wait on A lands here, after compute
    __syncthreads();           // single barrier per iteration
  }

  // ---- epilogue: C/D layout col=lane&15, row=(lane>>4)*4+r   [m89]
  float* P = partial + ((size_t)ks * BATCH + m0) * 256;
#pragma unroll
  for (int mf = 0; mf < 8; ++mf) {
    int row = wm * 128 + mf * 16 + l4 * 4;
#pragma unroll
    for (int nf = 0; nf < 4; ++nf) {
      int col = wn * 64 + nf * 16 + l15;
#pragma unroll
      for (int rr = 0; rr < 4; ++rr)
        P[(size_t)(row + rr) * 256 + col] = acc[mf][nf][rr];
    }
  }
}

// ---------------- tail: partial-reduce + pov mix + relu + fc0..fc3 ----------------
__global__ __launch_bounds__(256)
void nnue_tail(const float* __restrict__ partial, int S,
               const float* __restrict__ pov,
               const float* __restrict__ waffb, const float* __restrict__ baffb,
               const float* __restrict__ fc0W, const float* __restrict__ fc0b,
               const float* __restrict__ fc1W, const float* __restrict__ fc1b,
               const float* __restrict__ fc2W, const float* __restrict__ fc2b,
               const float* __restrict__ fc3W, const float* __restrict__ fc3b,
               float* __restrict__ out) {
  __shared__ float w0s[32 * 256];   // stored at [(j<<8) | ((k+j)&255)]
  __shared__ float w1s[32 * 32];    // [(j<<5) | ((k+j)&31)]
  __shared__ float w2s[32 * 64];    // [(j<<6) | ((k+j)&63)]
  __shared__ float w3s[96];
  __shared__ float b0s[32], b1s[32], b2s[32];
  __shared__ float base_s[4][256];
  __shared__ float b3s;

  const int t = threadIdx.x;
  for (int i = t; i < 8192; i += 256) { int j = i >> 8, k = i & 255; w0s[(j << 8) | ((k + j) & 255)] = fc0W[i]; }
  for (int i = t; i < 1024; i += 256) { int j = i >> 5, k = i & 31;  w1s[(j << 5) | ((k + j) & 31)]  = fc1W[i]; }
  for (int i = t; i < 2048; i += 256) { int j = i >> 6, k = i & 63;  w2s[(j << 6) | ((k + j) & 63)]  = fc2W[i]; }
  if (t < 96) w3s[t] = fc3W[t];
  if (t < 32) { b0s[t] = fc0b[t]; b1s[t] = fc1b[t]; b2s[t] = fc2b[t]; }
  if (t == 0) b3s = fc3b[0];
  __syncthreads();

  const int wid = t >> 6, lane = t & 63;
  const int m = blockIdx.x * 4 + wid;
  const float pv = pov[m];

  // lane l holds concat[w_,b_] cols 4l..4l+3 (summed over K-splits, +bias)
  float val[4];
  {
    const float* p = partial + (size_t)m * 256 + lane * 4;
    fvec4 a = *(const fvec4*)p;
    for (int s = 1; s < S; ++s) a += *(const fvec4*)(p + (size_t)s * BATCH * 256);
    const int c0 = lane * 4;
#pragma unroll
    for (int j = 0; j < 4; ++j) {
      int c = c0 + j;
      float bias = (c < 128) ? waffb[c] : baffb[c - 128];
      val[j] = a[j] + bias;
    }
  }
#pragma unroll
  for (int j = 0; j < 4; ++j) {
    float other = __shfl(val[j], lane ^ 32, 64);   // partner holds the b_/w_ counterpart
    if (lane < 32) {
      int c = lane * 4 + j;
      float w = val[j], b = other;
      base_s[wid][c]       = fmaxf(pv * w + (1.f - pv) * b, 0.f);
      base_s[wid][c + 128] = fmaxf(pv * b + (1.f - pv) * w, 0.f);
    }
  }
  __syncthreads();

  const int j = lane & 31, half = lane >> 5;
  const float* bs = &base_s[wid][0];

  // fc0: each (j,half) pair sums 128 terms, then combines across halves
  float s0 = 0.f;
  for (int k = 0; k < 128; ++k) {
    int kk = half * 128 + k;
    s0 += bs[kk] * w0s[(j << 8) | ((kk + j) & 255)];
  }
  s0 += __shfl(s0, lane ^ 32, 64);
  float x0 = fmaxf(s0 + b0s[j], 0.f);

  // fc1 (32x32)
  float s1 = 0.f;
  for (int k = 0; k < 32; ++k)
    s1 += __shfl(x0, k, 64) * w1s[(j << 5) | ((k + j) & 31)];
  float x1 = fmaxf(s1 + b1s[j], 0.f);

  // fc2 (32x64), input = [x0, x1]
  float s2 = 0.f;
  for (int k = 0; k < 32; ++k) {
    s2 += __shfl(x0, k, 64) * w2s[(j << 6) | ((k + j) & 63)];
    s2 += __shfl(x1, k, 64) * w2s[(j << 6) | ((k + 32 + j) & 63)];
  }
  float x2 = fmaxf(s2 + b2s[j], 0.f);

  // fc3 (1x96), input = [x0, x1, x2]
  float s3 = 0.f;
  for (int k = 0; k < 32; ++k) {
    s3 += __shfl(x0, k, 64) * w3s[k];
    s3 += __shfl(x1, k, 64) * w3s[32 + k];
    s3 += __shfl(x2, k, 64) * w3s[64 + k];
  }
  if (lane == 0) out[m] = s3 + b3s;
}

extern "C" void kernel_launch(void* const* d_in, const int* in_sizes, int n_in,
                              void* d_out, int out_size, void* d_ws, size_t ws_size,
                              hipStream_t stream) {
  const float* pov   = (const float*)d_in[0];
  const float* white = (const float*)d_in[1];
  const float* black = (const float*)d_in[2];
  const float* wW    = (const float*)d_in[3];
  const float* wb    = (const float*)d_in[4];
  const float* bW    = (const float*)d_in[5];
  const float* bb    = (const float*)d_in[6];
  const float* fc0W  = (const float*)d_in[7];
  const float* fc0b  = (const float*)d_in[8];
  const float* fc1W  = (const float*)d_in[9];
  const float* fc1b  = (const float*)d_in[10];
  const float* fc2W  = (const float*)d_in[11];
  const float* fc2b  = (const float*)d_in[12];
  const float* fc3W  = (const float*)d_in[13];
  const float* fc3b  = (const float*)d_in[14];
  float* out = (float*)d_out;

  short* Bprep = (short*)d_ws;
  const size_t BWS_BYTES = (size_t)256 * NUMELK * 2;      // 25,165,824
  float* partial = (float*)((char*)d_ws + BWS_BYTES);
  const size_t PART1 = (size_t)BATCH * 256 * 4;           // 8,388,608

  int S = 8;                                              // K-split: 256 blocks = 1/CU
  if (ws_size < BWS_BYTES + 8 * PART1) S = 4;
  if (ws_size < BWS_BYTES + 4 * PART1) S = 2;
  if (ws_size < BWS_BYTES + 2 * PART1) S = 1;

  nnue_prep<<<dim3(6144), 256, 0, stream>>>(wW, bW, Bprep);
  nnue_gemm<<<dim3(32 * S), 512, 0, stream>>>(white, black, Bprep, partial, NUMELK / S, S);
  nnue_tail<<<dim3(BATCH / 4), 256, 0, stream>>>(partial, S, pov, wb, bb,
      fc0W, fc0b, fc1W, fc1b, fc2W, fc2b, fc3W, fc3b, out);
}

// Round 6
// 420.519 us; speedup vs baseline: 1.3498x; 1.0633x over previous
//
#include <hip/hip_runtime.h>
#include <hip/hip_bf16.h>
#include <stdint.h>

typedef float f32x4 __attribute__((ext_vector_type(4)));
typedef float fvec4 __attribute__((ext_vector_type(4)));
typedef short bf16x8 __attribute__((ext_vector_type(8)));
typedef short bf16x4 __attribute__((ext_vector_type(4)));

#define HALF_K 24576
#define NUMELK 49152
#define BATCH  8192
#define BM 256
#define BN 256
#define BK 64

__device__ __forceinline__ short f2bf(float f) {
  __hip_bfloat16 h = __float2bfloat16(f);
  return __builtin_bit_cast(short, h);
}

// global->LDS DMA, 16B per lane. LDS dest is wave-uniform base (+lane*16 by HW);
// global src is per-lane.
__device__ __forceinline__ void gload_lds16(const short* g, short* l) {
  __builtin_amdgcn_global_load_lds(
      (const __attribute__((address_space(1))) unsigned*)g,
      (__attribute__((address_space(3))) unsigned*)l, 16, 0, 0);
}

// ---------------- prep: B pre-tiled + pre-swizzled bf16 ----------------
// Logical B[col][k], col 0..255 over combined-K (col<128: w_aff_W row col;
// col>=128: b_aff_W row col-128 with K-halves swapped).
// Stored as per-K-tile contiguous 32KB tiles so gemm can global_load_lds it:
//   Bprep[KT*16384 + col*64 + ((kc ^ (col&7))<<3) + e],  k = KT*64 + kc*8 + e
__global__ __launch_bounds__(256)
void nnue_prep(const float* __restrict__ wW, const float* __restrict__ bW,
               short* __restrict__ Bprep) {
  int gid = blockIdx.x * 256 + threadIdx.x;   // grid 6144 -> 1,572,864 chunks
  int KT  = gid >> 11;                        // 0..767
  int rem = gid & 2047;
  int col = rem >> 3;                         // 0..255
  int kc  = rem & 7;
  int kg  = KT * 64 + kc * 8;
  const float* src;
  if (col < 128) {
    src = wW + (size_t)col * NUMELK + kg;
  } else {
    int kk = (kg < HALF_K) ? (kg + HALF_K) : (kg - HALF_K);
    src = bW + (size_t)(col - 128) * NUMELK + kk;
  }
  fvec4 v0 = ((const fvec4*)src)[0];
  fvec4 v1 = ((const fvec4*)src)[1];
  bf16x8 o;
  o[0] = f2bf(v0[0]); o[1] = f2bf(v0[1]); o[2] = f2bf(v0[2]); o[3] = f2bf(v0[3]);
  o[4] = f2bf(v1[0]); o[5] = f2bf(v1[1]); o[6] = f2bf(v1[2]); o[7] = f2bf(v1[3]);
  *(bf16x8*)(Bprep + (size_t)KT * 16384 + col * 64 + ((kc ^ (col & 7)) << 3)) = o;
}

// ---------------- main GEMM: [8192 x 49152] x [49152 x 256] ----------------
// 256x256 tile, BK=64, 8 waves (2M x 4N), per-wave 128x64 output, acc[8][4].
// STATIC double-buffer (A0/A1/B0/B1 as distinct __shared__ objects, 2x
// unrolled loop) so the compiler can PROVE the in-flight DMA / ds_writes
// don't alias the ds_reads -> no defensive vmcnt drain before compute.
// sched_barrier(0) fences pin {issue} -> {ds_read+MFMA} -> {cvt+writeA}.
// A issued before B so cvt waits vmcnt(4) (A only); B-DMA drains for free at
// __syncthreads (issued a full compute phase earlier, L2-resident).
__global__ __launch_bounds__(512, 1)
void nnue_gemm(const float* __restrict__ white, const float* __restrict__ black,
               const short* __restrict__ Bprep, float* __restrict__ partial,
               int kchunk, int S) {
  __shared__ short A0s[BM * BK];
  __shared__ short A1s[BM * BK];
  __shared__ short B0s[BN * BK];
  __shared__ short B1s[BN * BK];

  const int t    = threadIdx.x;
  const int lane = t & 63;
  const int wid  = t >> 6;

  // XCD-grouped decode: blocks on one XCD share ks (same B chunk in its L2)
  const int bid = blockIdx.x;          // 32*S blocks
  const int xcd = bid & 7, i = bid >> 3;
  const int xpk = 8 / S;               // S in {1,2,4,8}
  const int ks  = xcd / xpk;
  const int mt  = (xcd % xpk) * (32 / xpk) + i;
  const int m0  = mt * BM;
  const int k0  = ks * kchunk;
  const int KT0 = k0 / BK;

  f32x4 acc[8][4];
  const f32x4 zero = {0.f, 0.f, 0.f, 0.f};
#pragma unroll
  for (int a = 0; a < 8; ++a)
#pragma unroll
    for (int b = 0; b < 4; ++b) acc[a][b] = zero;

  const int wm = wid >> 2, wn = wid & 3;
  const int l15 = lane & 15, l4 = lane >> 4;

  // A staging map: pass j (0..7): thread t covers row 32j + (t>>4),
  // 16B fp32 chunk (t&15) within the row's 64 floats.
  const int rbase = t >> 4;            // 0..31
  const int cchunk = t & 15;           // 16B fp32 chunk (4 floats)
  const size_t a_off = (size_t)(m0 + rbase) * HALF_K + cchunk * 4;
  const int swz = ((cchunk >> 1) ^ (rbase & 7)) << 3;  // loop-invariant
  const int halfsh = (cchunk & 1) * 4;                 // shorts offset of 8B half

  fvec4 va[8];               // 32 VGPR A staging (one tile in flight)

  auto issueA = [&](int kg) {
    const float* A; int ka;
    if (kg < HALF_K) { A = white; ka = kg; } else { A = black; ka = kg - HALF_K; }
    const float* base = A + a_off + ka;
#pragma unroll
    for (int j = 0; j < 8; ++j)
      va[j] = *(const fvec4*)(base + (size_t)32 * j * HALF_K);
  };

  auto issueB = [&](int kt_glob, short* Bdst) {
    const short* src = Bprep + (size_t)kt_glob * (BN * BK) + wid * 2048 + lane * 8;
    short* dst = Bdst + wid * 2048;
#pragma unroll
    for (int j = 0; j < 4; ++j)
      gload_lds16(src + j * 512, dst + j * 512);
  };

  auto writeA = [&](short* Adst) {
#pragma unroll
    for (int j = 0; j < 8; ++j) {
      int row = 32 * j + rbase;
      bf16x4 o;
      o[0] = f2bf(va[j][0]); o[1] = f2bf(va[j][1]);
      o[2] = f2bf(va[j][2]); o[3] = f2bf(va[j][3]);
      *(bf16x4*)&Adst[row * 64 + swz + halfsh] = o;
    }
  };

  auto compute = [&](const short* Ab, const short* Bb) {
#pragma unroll
    for (int kstep = 0; kstep < 2; ++kstep) {
      const int kc = kstep * 4 + l4;
      bf16x8 bfr[4];
#pragma unroll
      for (int nf = 0; nf < 4; ++nf) {
        int col = wn * 64 + nf * 16 + l15;
        bfr[nf] = *(const bf16x8*)&Bb[col * 64 + ((kc ^ (col & 7)) << 3)];
      }
#pragma unroll
      for (int mf = 0; mf < 8; ++mf) {
        int row = wm * 128 + mf * 16 + l15;
        bf16x8 af = *(const bf16x8*)&Ab[row * 64 + ((kc ^ (row & 7)) << 3)];
#pragma unroll
        for (int nf = 0; nf < 4; ++nf)
          acc[mf][nf] = __builtin_amdgcn_mfma_f32_16x16x32_bf16(af, bfr[nf], acc[mf][nf], 0, 0, 0);
      }
    }
  };

  const int niter = kchunk / BK;   // even for all S in {1,2,4,8}

  // prologue: tile 0 -> A0/B0
  issueA(k0);
  issueB(KT0, B0s);
  __builtin_amdgcn_sched_barrier(0);
  writeA(A0s);                 // vmcnt(4): waits A only, B0 DMA stays in flight
  __syncthreads();             // drains B0 (one-time cost)

  for (int kt = 0; kt < niter; kt += 2) {
    // ---- half 1: compute (A0,B0); stage tile kt+1 -> (A1,B1)
    issueA(k0 + (kt + 1) * BK);          // queue: [A x8, ...]
    issueB(KT0 + kt + 1, B1s);           // queue: [A x8, B x4]
    __builtin_amdgcn_sched_barrier(0);   // loads pinned above compute
    compute(A0s, B0s);
    __builtin_amdgcn_sched_barrier(0);   // cvt pinned below compute
    writeA(A1s);                         // vmcnt(4): A done, B1 in flight
    __syncthreads();                     // drain: B1 issued ~1 phase ago -> free

    // ---- half 2: compute (A1,B1); stage tile kt+2 -> (A0,B0)
    const bool h2 = (kt + 2 < niter);
    if (h2) {
      issueA(k0 + (kt + 2) * BK);
      issueB(KT0 + kt + 2, B0s);
    }
    __builtin_amdgcn_sched_barrier(0);
    compute(A1s, B1s);
    __builtin_amdgcn_sched_barrier(0);
    if (h2) writeA(A0s);
    __syncthreads();
  }

  // ---- epilogue: C/D layout col=lane&15, row=(lane>>4)*4+r   [m89]
  float* P = partial + ((size_t)ks * BATCH + m0) * 256;
#pragma unroll
  for (int mf = 0; mf < 8; ++mf) {
    int row = wm * 128 + mf * 16 + l4 * 4;
#pragma unroll
    for (int nf = 0; nf < 4; ++nf) {
      int col = wn * 64 + nf * 16 + l15;
#pragma unroll
      for (int rr = 0; rr < 4; ++rr)
        P[(size_t)(row + rr) * 256 + col] = acc[mf][nf][rr];
    }
  }
}

// ---------------- tail: partial-reduce + pov mix + relu + fc0..fc3 ----------------
__global__ __launch_bounds__(256)
void nnue_tail(const float* __restrict__ partial, int S,
               const float* __restrict__ pov,
               const float* __restrict__ waffb, const float* __restrict__ baffb,
               const float* __restrict__ fc0W, const float* __restrict__ fc0b,
               const float* __restrict__ fc1W, const float* __restrict__ fc1b,
               const float* __restrict__ fc2W, const float* __restrict__ fc2b,
               const float* __restrict__ fc3W, const float* __restrict__ fc3b,
               float* __restrict__ out) {
  __shared__ float w0s[32 * 256];   // stored at [(j<<8) | ((k+j)&255)]
  __shared__ float w1s[32 * 32];    // [(j<<5) | ((k+j)&31)]
  __shared__ float w2s[32 * 64];    // [(j<<6) | ((k+j)&63)]
  __shared__ float w3s[96];
  __shared__ float b0s[32], b1s[32], b2s[32];
  __shared__ float base_s[4][256];
  __shared__ float b3s;

  const int t = threadIdx.x;
  for (int i = t; i < 8192; i += 256) { int j = i >> 8, k = i & 255; w0s[(j << 8) | ((k + j) & 255)] = fc0W[i]; }
  for (int i = t; i < 1024; i += 256) { int j = i >> 5, k = i & 31;  w1s[(j << 5) | ((k + j) & 31)]  = fc1W[i]; }
  for (int i = t; i < 2048; i += 256) { int j = i >> 6, k = i & 63;  w2s[(j << 6) | ((k + j) & 63)]  = fc2W[i]; }
  if (t < 96) w3s[t] = fc3W[t];
  if (t < 32) { b0s[t] = fc0b[t]; b1s[t] = fc1b[t]; b2s[t] = fc2b[t]; }
  if (t == 0) b3s = fc3b[0];
  __syncthreads();

  const int wid = t >> 6, lane = t & 63;
  const int m = blockIdx.x * 4 + wid;
  const float pv = pov[m];

  // lane l holds concat[w_,b_] cols 4l..4l+3 (summed over K-splits, +bias)
  float val[4];
  {
    const float* p = partial + (size_t)m * 256 + lane * 4;
    fvec4 a = *(const fvec4*)p;
    for (int s = 1; s < S; ++s) a += *(const fvec4*)(p + (size_t)s * BATCH * 256);
    const int c0 = lane * 4;
#pragma unroll
    for (int j = 0; j < 4; ++j) {
      int c = c0 + j;
      float bias = (c < 128) ? waffb[c] : baffb[c - 128];
      val[j] = a[j] + bias;
    }
  }
#pragma unroll
  for (int j = 0; j < 4; ++j) {
    float other = __shfl(val[j], lane ^ 32, 64);   // partner holds the b_/w_ counterpart
    if (lane < 32) {
      int c = lane * 4 + j;
      float w = val[j], b = other;
      base_s[wid][c]       = fmaxf(pv * w + (1.f - pv) * b, 0.f);
      base_s[wid][c + 128] = fmaxf(pv * b + (1.f - pv) * w, 0.f);
    }
  }
  __syncthreads();

  const int j = lane & 31, half = lane >> 5;
  const float* bs = &base_s[wid][0];

  // fc0: each (j,half) pair sums 128 terms, then combines across halves
  float s0 = 0.f;
  for (int k = 0; k < 128; ++k) {
    int kk = half * 128 + k;
    s0 += bs[kk] * w0s[(j << 8) | ((kk + j) & 255)];
  }
  s0 += __shfl(s0, lane ^ 32, 64);
  float x0 = fmaxf(s0 + b0s[j], 0.f);

  // fc1 (32x32)
  float s1 = 0.f;
  for (int k = 0; k < 32; ++k)
    s1 += __shfl(x0, k, 64) * w1s[(j << 5) | ((k + j) & 31)];
  float x1 = fmaxf(s1 + b1s[j], 0.f);

  // fc2 (32x64), input = [x0, x1]
  float s2 = 0.f;
  for (int k = 0; k < 32; ++k) {
    s2 += __shfl(x0, k, 64) * w2s[(j << 6) | ((k + j) & 63)];
    s2 += __shfl(x1, k, 64) * w2s[(j << 6) | ((k + 32 + j) & 63)];
  }
  float x2 = fmaxf(s2 + b2s[j], 0.f);

  // fc3 (1x96), input = [x0, x1, x2]
  float s3 = 0.f;
  for (int k = 0; k < 32; ++k) {
    s3 += __shfl(x0, k, 64) * w3s[k];
    s3 += __shfl(x1, k, 64) * w3s[32 + k];
    s3 += __shfl(x2, k, 64) * w3s[64 + k];
  }
  if (lane == 0) out[m] = s3 + b3s;
}

extern "C" void kernel_launch(void* const* d_in, const int* in_sizes, int n_in,
                              void* d_out, int out_size, void* d_ws, size_t ws_size,
                              hipStream_t stream) {
  const float* pov   = (const float*)d_in[0];
  const float* white = (const float*)d_in[1];
  const float* black = (const float*)d_in[2];
  const float* wW    = (const float*)d_in[3];
  const float* wb    = (const float*)d_in[4];
  const float* bW    = (const float*)d_in[5];
  const float* bb    = (const float*)d_in[6];
  const float* fc0W  = (const float*)d_in[7];
  const float* fc0b  = (const float*)d_in[8];
  const float* fc1W  = (const float*)d_in[9];
  const float* fc1b  = (const float*)d_in[10];
  const float* fc2W  = (const float*)d_in[11];
  const float* fc2b  = (const float*)d_in[12];
  const float* fc3W  = (const float*)d_in[13];
  const float* fc3b  = (const float*)d_in[14];
  float* out = (float*)d_out;

  short* Bprep = (short*)d_ws;
  const size_t BWS_BYTES = (size_t)256 * NUMELK * 2;      // 25,165,824
  float* partial = (float*)((char*)d_ws + BWS_BYTES);
  const size_t PART1 = (size_t)BATCH * 256 * 4;           // 8,388,608

  int S = 8;                                              // K-split: 256 blocks = 1/CU
  if (ws_size < BWS_BYTES + 8 * PART1) S = 4;
  if (ws_size < BWS_BYTES + 4 * PART1) S = 2;
  if (ws_size < BWS_BYTES + 2 * PART1) S = 1;

  nnue_prep<<<dim3(6144), 256, 0, stream>>>(wW, bW, Bprep);
  nnue_gemm<<<dim3(32 * S), 512, 0, stream>>>(white, black, Bprep, partial, NUMELK / S, S);
  nnue_tail<<<dim3(BATCH / 4), 256, 0, stream>>>(partial, S, pov, wb, bb,
      fc0W, fc0b, fc1W, fc1b, fc2W, fc2b, fc3W, fc3b, out);
}